// Round 5
// baseline (49.556 us; speedup 1.0000x reference)
//
#include <hip/hip_runtime.h>
#include <math.h>

#define NB 32      // B
#define NV 1024    // V
#define NFT 16     // F
#define NA 32      // A
#define NP 64      // P
#define NOUT 128   // NF
#define NC 96      // C = P + A
#define NC2 192    // 2C

#define NSPLIT 16            // V splits
#define VPB 64               // NV/NSPLIT rows per block

// ---------------------------------------------------------------------------
// K2p: fused vertex transform + partial (max,sum) aggregation over a 64-row
// V-slice. grid (B, NSPLIT), 256 threads.
//  phase A: c = tid&127 (active c<96), rh = tid>>7 (wave-uniform row half).
//           x rows read via wave-uniform scalar loads (readfirstlane'd row
//           index -> s_load); W column in VGPRs; f tile written to LDS.
//  phase B: thread owns 4a x 3c tile; per row: 1 float4 broadcast e-read +
//           3 conflict-free b32 f-reads -> 12 products.
// part layout: part[((b*16+vs)*32 + a)*192 + c] = max ; +96+c = sum
// ---------------------------------------------------------------------------
__global__ void k2p(const float* __restrict__ x,
                    const float* __restrict__ W_flr,
                    const float* __restrict__ b_flr,
                    const float* __restrict__ W_s,
                    const float* __restrict__ b_s,
                    float* __restrict__ ewbuf,
                    float* __restrict__ part) {
    __shared__ float fs[VPB][NC];    // 24 KB

    int b = blockIdx.x, vs = blockIdx.y, tid = threadIdx.x;
    int rowbase = b * NV + vs * VPB;

    // phase A: compute f tile. c = tid&127 (<96 active), rh = tid>>7 uniform.
    {
        int c  = tid & 127;
        int rh = tid >> 7;
        if (c < NC) {
            float Wcol[NFT], bias;
            if (c < NP) {
                bias = b_flr[c];
#pragma unroll
                for (int k = 0; k < NFT; ++k) Wcol[k] = W_flr[k * NP + c];
            } else {
                int a = c - NP;
                bias = b_s[a];
#pragma unroll
                for (int k = 0; k < NFT; ++k) Wcol[k] = W_s[k * NA + a];
            }
#pragma unroll
            for (int r0 = 0; r0 < 32; ++r0) {
                int rloc = rh * 32 + r0;
                int row = __builtin_amdgcn_readfirstlane(rowbase + rloc);
                const float* xr = x + (size_t)row * NFT;   // uniform -> s_load
                float acc = bias;
#pragma unroll
                for (int k = 0; k < NFT; ++k)
                    acc = fmaf(xr[k], Wcol[k], acc);
                if (c >= NP) {
                    acc = __expf(-acc * acc);
                    ewbuf[(size_t)row * NA + (c - NP)] = acc;
                }
                fs[rloc][c] = acc;
            }
        }
    }
    __syncthreads();

    // phase B: reduction. at = tid>>5 (a-quad), ct = tid&31 (c-triple)
    int at = tid >> 5, ct = tid & 31;
    int cbase = ct * 3;
    float sm[4][3], mx[4][3];
#pragma unroll
    for (int i = 0; i < 4; ++i)
#pragma unroll
        for (int j = 0; j < 3; ++j) { sm[i][j] = 0.f; mx[i][j] = -INFINITY; }

    for (int r = 0; r < VPB; ++r) {
        float4 e4 = *(const float4*)&fs[r][NP + at * 4];
        float f0 = fs[r][cbase], f1 = fs[r][cbase + 1], f2 = fs[r][cbase + 2];
        float ee[4] = {e4.x, e4.y, e4.z, e4.w};
#pragma unroll
        for (int i = 0; i < 4; ++i) {
            float p0 = ee[i] * f0, p1 = ee[i] * f1, p2 = ee[i] * f2;
            sm[i][0] += p0; sm[i][1] += p1; sm[i][2] += p2;
            mx[i][0] = fmaxf(mx[i][0], p0);
            mx[i][1] = fmaxf(mx[i][1], p1);
            mx[i][2] = fmaxf(mx[i][2], p2);
        }
    }

    float* pb = part + (size_t)((b * NSPLIT + vs) * NA) * NC2;
#pragma unroll
    for (int i = 0; i < 4; ++i) {
        int a = at * 4 + i;
#pragma unroll
        for (int j = 0; j < 3; ++j) {
            pb[a * NC2 + cbase + j]      = mx[i][j];
            pb[a * NC2 + NC + cbase + j] = sm[i][j];
        }
    }
}

// ---------------------------------------------------------------------------
// K23: combine NSPLIT partials -> agg row (in LDS) -> G matmul.
// grid (B, A), 192 threads.
// Gp[(b*32+a)*128+n] = W_out[(16+32*192+a)*128+n] + sum_c agg[c]*W_out[(16+a*192+c)*128+n]
// ---------------------------------------------------------------------------
__global__ void k23(const float* __restrict__ part,
                    const float* __restrict__ W_out,
                    float* __restrict__ Gp) {
    __shared__ float aggL[NC2];
    int b = blockIdx.x, a = blockIdx.y, tid = threadIdx.x;

    // combine: thread j<96 does max over vs; j in [96,192) does sum
    {
        const float* pb = part + (size_t)(b * NSPLIT * NA + a) * NC2 + tid;
        const size_t stride = (size_t)NA * NC2;
        if (tid < NC) {
            float m = -INFINITY;
#pragma unroll
            for (int vsi = 0; vsi < NSPLIT; ++vsi)
                m = fmaxf(m, pb[vsi * stride]);
            aggL[tid] = m;
        } else {
            float s = 0.f;
#pragma unroll
            for (int vsi = 0; vsi < NSPLIT; ++vsi)
                s += pb[vsi * stride];
            aggL[tid] = s * (1.0f / (float)NV);
        }
    }
    __syncthreads();

    if (tid < NOUT) {
        int n = tid;
        const float* wr = W_out + (size_t)(NFT + a * NC2) * NOUT + n;
        float acc = W_out[(size_t)(NFT + NA * NC2 + a) * NOUT + n];
#pragma unroll 8
        for (int c = 0; c < NC2; ++c)
            acc = fmaf(aggL[c], wr[(size_t)c * NOUT], acc);
        Gp[(size_t)(b * NA + a) * NOUT + n] = acc;
    }
}

// ---------------------------------------------------------------------------
// K4: out[b,v,n] = tanh( b_out[n] + sum_k x[b,v,k]*W_out[k*128+n]
//                        + sum_a ew[b,v,a]*Gp[b,a,n] )
// NO LDS: W_out column (16) + Gp column (32) in VGPRs; row data (x, ew) read
// via wave-uniform scalar loads (readfirstlane'd row index -> s_load).
// block = (b, 32-row chunk); 256 thr: n = tid&127, rg = tid>>7 (wave-uniform).
// ---------------------------------------------------------------------------
#define K4_ROWS 32
__global__ void k4_out(const float* __restrict__ x,
                       const float* __restrict__ ewbuf,
                       const float* __restrict__ Gp,
                       const float* __restrict__ W_out,
                       const float* __restrict__ b_out,
                       float* __restrict__ out) {
    int b     = blockIdx.x;
    int chunk = blockIdx.y;
    int tid   = threadIdx.x;
    int n  = tid & (NOUT - 1);
    int rg = tid >> 7;                   // 0 or 1, wave-uniform

    int rowbase = b * NV + chunk * K4_ROWS;

    // register-resident columns (coalesced global loads)
    float Wc[NFT], Gc[NA];
#pragma unroll
    for (int k = 0; k < NFT; ++k)
        Wc[k] = W_out[(size_t)k * NOUT + n];
    const float* gpb = Gp + ((size_t)b * NA) * NOUT + n;
#pragma unroll
    for (int a = 0; a < NA; ++a)
        Gc[a] = gpb[(size_t)a * NOUT];
    float bn = b_out[n];

    int row0 = rowbase + rg * 16;
    float* orow = out + (size_t)row0 * NOUT + n;
#pragma unroll
    for (int r = 0; r < 16; ++r) {
        int row = __builtin_amdgcn_readfirstlane(row0 + r);
        const float* xr = x + (size_t)row * NFT;       // uniform -> s_load
        const float* er = ewbuf + (size_t)row * NA;    // uniform -> s_load
        float s = bn;
#pragma unroll
        for (int k = 0; k < NFT; ++k)
            s = fmaf(xr[k], Wc[k], s);
#pragma unroll
        for (int a = 0; a < NA; ++a)
            s = fmaf(er[a], Gc[a], s);
        // fast tanh: clamp then (e-1)/(e+1), e = exp(2s)
        s = fminf(fmaxf(s, -15.f), 15.f);
        float e = __expf(2.f * s);
        orow[(size_t)r * NOUT] = (e - 1.f) * __builtin_amdgcn_rcpf(e + 1.f);
    }
}

// ---------------------------------------------------------------------------
extern "C" void kernel_launch(void* const* d_in, const int* in_sizes, int n_in,
                              void* d_out, int out_size, void* d_ws, size_t ws_size,
                              hipStream_t stream) {
    const float* x     = (const float*)d_in[0];
    const float* W_flr = (const float*)d_in[1];
    const float* b_flr = (const float*)d_in[2];
    const float* W_s   = (const float*)d_in[3];
    const float* b_s   = (const float*)d_in[4];
    const float* W_out = (const float*)d_in[5];
    const float* b_out = (const float*)d_in[6];
    float* out = (float*)d_out;

    // workspace layout (floats)
    float* ewbuf = (float*)d_ws;                              // B*V*32        = 1,048,576
    float* part  = ewbuf + (size_t)NB * NV * NA;              // 512*32*192    = 3,145,728
    float* Gp    = part  + (size_t)NB * NSPLIT * NA * NC2;    // B*A*128       =   131,072

    // K2p: grid (B, 16) x 256
    {
        dim3 g(NB, NSPLIT);
        k2p<<<g, 256, 0, stream>>>(x, W_flr, b_flr, W_s, b_s, ewbuf, part);
    }
    // K23: grid (B, A) x 192
    {
        dim3 g(NB, NA);
        k23<<<g, 192, 0, stream>>>(part, W_out, Gp);
    }
    // K4: grid (B, 32) x 256
    {
        dim3 g(NB, NV / K4_ROWS);
        k4_out<<<g, 256, 0, stream>>>(x, ewbuf, Gp, W_out, b_out, out);
    }
}

// Round 6
// 42.461 us; speedup vs baseline: 1.1671x; 1.1671x over previous
//
#include <hip/hip_runtime.h>
#include <math.h>

#define NB 32      // B
#define NV 1024    // V
#define NFT 16     // F
#define NA 32      // A
#define NP 64      // P
#define NOUT 128   // NF
#define NC 96      // C = P + A
#define NC2 192    // 2C

#define NSPLIT 16            // V splits
#define VPB 64               // NV/NSPLIT rows per block

// ---------------------------------------------------------------------------
// K2p: fused vertex transform + partial (max,sum) aggregation over a 64-row
// V-slice. grid (B, NSPLIT), 256 threads.
//  phase A (192 active): c = tid&127 (<96), rh = tid>>7. W column in VGPRs;
//          x rows read from staged LDS via float4 (4 x b128 per row).
//  phase B: thread owns 4a x 3c tile; per row: 1 float4 broadcast e-read +
//          3 b32 f-reads -> 12 products.
// part layout: part[((b*16+vs)*32 + a)*192 + c] = max ; +96+c = sum
// ---------------------------------------------------------------------------
__global__ void k2p(const float* __restrict__ x,
                    const float* __restrict__ W_flr,
                    const float* __restrict__ b_flr,
                    const float* __restrict__ W_s,
                    const float* __restrict__ b_s,
                    float* __restrict__ ewbuf,
                    float* __restrict__ part) {
    __shared__ float xs[VPB][NFT];   // 4 KB
    __shared__ float fs[VPB][NC];    // 24 KB

    int b = blockIdx.x, vs = blockIdx.y, tid = threadIdx.x;
    int rowbase = b * NV + vs * VPB;

    // stage x: 64*16 = 1024 floats = 256 float4, fully coalesced
    {
        const float4* xsrc = (const float4*)(x + (size_t)rowbase * NFT);
        ((float4*)xs)[tid] = xsrc[tid];
    }
    __syncthreads();

    // phase A: compute f tile. c = tid&127 (<96 active), rh = tid>>7.
    {
        int c  = tid & 127;
        int rh = tid >> 7;
        if (c < NC) {
            float Wcol[NFT], bias;
            if (c < NP) {
                bias = b_flr[c];
#pragma unroll
                for (int k = 0; k < NFT; ++k) Wcol[k] = W_flr[k * NP + c];
            } else {
                int a = c - NP;
                bias = b_s[a];
#pragma unroll
                for (int k = 0; k < NFT; ++k) Wcol[k] = W_s[k * NA + a];
            }
#pragma unroll
            for (int r0 = 0; r0 < 32; ++r0) {
                int r = rh * 32 + r0;
                // row via 4 x ds_read_b128 into registers
                float xr[NFT];
#pragma unroll
                for (int q = 0; q < 4; ++q)
                    ((float4*)xr)[q] = ((const float4*)xs[r])[q];
                float acc = bias;
#pragma unroll
                for (int k = 0; k < NFT; ++k)
                    acc = fmaf(xr[k], Wcol[k], acc);
                if (c >= NP) {
                    acc = __expf(-acc * acc);
                    ewbuf[(size_t)(rowbase + r) * NA + (c - NP)] = acc;
                }
                fs[r][c] = acc;
            }
        }
    }
    __syncthreads();

    // phase B: reduction. at = tid>>5 (a-quad), ct = tid&31 (c-triple)
    int at = tid >> 5, ct = tid & 31;
    int cbase = ct * 3;
    float sm[4][3], mx[4][3];
#pragma unroll
    for (int i = 0; i < 4; ++i)
#pragma unroll
        for (int j = 0; j < 3; ++j) { sm[i][j] = 0.f; mx[i][j] = -INFINITY; }

    for (int r = 0; r < VPB; ++r) {
        float4 e4 = *(const float4*)&fs[r][NP + at * 4];
        float f0 = fs[r][cbase], f1 = fs[r][cbase + 1], f2 = fs[r][cbase + 2];
        float ee[4] = {e4.x, e4.y, e4.z, e4.w};
#pragma unroll
        for (int i = 0; i < 4; ++i) {
            float p0 = ee[i] * f0, p1 = ee[i] * f1, p2 = ee[i] * f2;
            sm[i][0] += p0; sm[i][1] += p1; sm[i][2] += p2;
            mx[i][0] = fmaxf(mx[i][0], p0);
            mx[i][1] = fmaxf(mx[i][1], p1);
            mx[i][2] = fmaxf(mx[i][2], p2);
        }
    }

    float* pb = part + (size_t)((b * NSPLIT + vs) * NA) * NC2;
#pragma unroll
    for (int i = 0; i < 4; ++i) {
        int a = at * 4 + i;
#pragma unroll
        for (int j = 0; j < 3; ++j) {
            pb[a * NC2 + cbase + j]      = mx[i][j];
            pb[a * NC2 + NC + cbase + j] = sm[i][j];
        }
    }
}

// ---------------------------------------------------------------------------
// K23: combine NSPLIT partials -> agg row (in LDS) -> G matmul.
// grid (B, A), 192 threads.
// ---------------------------------------------------------------------------
__global__ void k23(const float* __restrict__ part,
                    const float* __restrict__ W_out,
                    float* __restrict__ Gp) {
    __shared__ float aggL[NC2];
    int b = blockIdx.x, a = blockIdx.y, tid = threadIdx.x;

    {
        const float* pb = part + (size_t)(b * NSPLIT * NA + a) * NC2 + tid;
        const size_t stride = (size_t)NA * NC2;
        if (tid < NC) {
            float m = -INFINITY;
#pragma unroll
            for (int vsi = 0; vsi < NSPLIT; ++vsi)
                m = fmaxf(m, pb[vsi * stride]);
            aggL[tid] = m;
        } else {
            float s = 0.f;
#pragma unroll
            for (int vsi = 0; vsi < NSPLIT; ++vsi)
                s += pb[vsi * stride];
            aggL[tid] = s * (1.0f / (float)NV);
        }
    }
    __syncthreads();

    if (tid < NOUT) {
        int n = tid;
        const float* wr = W_out + (size_t)(NFT + a * NC2) * NOUT + n;
        float acc = W_out[(size_t)(NFT + NA * NC2 + a) * NOUT + n];
#pragma unroll 8
        for (int c = 0; c < NC2; ++c)
            acc = fmaf(aggL[c], wr[(size_t)c * NOUT], acc);
        Gp[(size_t)(b * NA + a) * NOUT + n] = acc;
    }
}

// ---------------------------------------------------------------------------
// K4: out[b,v,n] = tanh( b_out[n] + sum_k x[b,v,k]*W_out[k*128+n]
//                        + sum_a ew[b,v,a]*Gp[b,a,n] )
// block = (b, 32-row chunk); 256 thr: n = tid&127, rg = tid>>7.
// W_out column (16) + Gp column (32) in registers; x/ew staged in LDS,
// read back per-row as float4 (12 x ds_read_b128 per row, not 48 b32).
// ---------------------------------------------------------------------------
#define K4_ROWS 32
__global__ void k4_out(const float* __restrict__ x,
                       const float* __restrict__ ewbuf,
                       const float* __restrict__ Gp,
                       const float* __restrict__ W_out,
                       const float* __restrict__ b_out,
                       float* __restrict__ out) {
    __shared__ float xs[K4_ROWS][NFT];   // 2 KB
    __shared__ float es[K4_ROWS][NA];    // 4 KB

    int b     = blockIdx.x;
    int chunk = blockIdx.y;
    int tid   = threadIdx.x;
    int n  = tid & (NOUT - 1);
    int rg = tid >> 7;                   // 0 or 1

    int rowbase = b * NV + chunk * K4_ROWS;

    // stage: ew rows (1024 floats = 256 float4), x rows (512 floats = 128 float4)
    {
        const float4* esrc = (const float4*)(ewbuf + (size_t)rowbase * NA);
        ((float4*)es)[tid] = esrc[tid];
        if (tid < 128) {
            const float4* xsrc = (const float4*)(x + (size_t)rowbase * NFT);
            ((float4*)xs)[tid] = xsrc[tid];
        }
    }

    // register-resident columns
    float Wc[NFT], Gc[NA];
#pragma unroll
    for (int k = 0; k < NFT; ++k)
        Wc[k] = W_out[(size_t)k * NOUT + n];
    const float* gpb = Gp + ((size_t)b * NA) * NOUT + n;
#pragma unroll
    for (int a = 0; a < NA; ++a)
        Gc[a] = gpb[(size_t)a * NOUT];
    float bn = b_out[n];

    __syncthreads();

    float* orow = out + ((size_t)rowbase + rg * 16) * NOUT + n;
#pragma unroll
    for (int r = 0; r < 16; ++r) {
        int row = rg * 16 + r;
        // pull row into registers via b128 reads
        float xr[NFT], er[NA];
#pragma unroll
        for (int q = 0; q < 4; ++q)
            ((float4*)xr)[q] = ((const float4*)xs[row])[q];
#pragma unroll
        for (int q = 0; q < 8; ++q)
            ((float4*)er)[q] = ((const float4*)es[row])[q];

        float s = bn;
#pragma unroll
        for (int k = 0; k < NFT; ++k)
            s = fmaf(xr[k], Wc[k], s);
#pragma unroll
        for (int a = 0; a < NA; ++a)
            s = fmaf(er[a], Gc[a], s);
        // fast tanh: clamp then (e-1)/(e+1), e = exp(2s)
        s = fminf(fmaxf(s, -15.f), 15.f);
        float e = __expf(2.f * s);
        orow[(size_t)r * NOUT] = (e - 1.f) * __builtin_amdgcn_rcpf(e + 1.f);
    }
}

// ---------------------------------------------------------------------------
extern "C" void kernel_launch(void* const* d_in, const int* in_sizes, int n_in,
                              void* d_out, int out_size, void* d_ws, size_t ws_size,
                              hipStream_t stream) {
    const float* x     = (const float*)d_in[0];
    const float* W_flr = (const float*)d_in[1];
    const float* b_flr = (const float*)d_in[2];
    const float* W_s   = (const float*)d_in[3];
    const float* b_s   = (const float*)d_in[4];
    const float* W_out = (const float*)d_in[5];
    const float* b_out = (const float*)d_in[6];
    float* out = (float*)d_out;

    // workspace layout (floats)
    float* ewbuf = (float*)d_ws;                              // B*V*32        = 1,048,576
    float* part  = ewbuf + (size_t)NB * NV * NA;              // 512*32*192    = 3,145,728
    float* Gp    = part  + (size_t)NB * NSPLIT * NA * NC2;    // B*A*128       =   131,072

    // K2p: grid (B, 16) x 256
    {
        dim3 g(NB, NSPLIT);
        k2p<<<g, 256, 0, stream>>>(x, W_flr, b_flr, W_s, b_s, ewbuf, part);
    }
    // K23: grid (B, A) x 192
    {
        dim3 g(NB, NA);
        k23<<<g, 192, 0, stream>>>(part, W_out, Gp);
    }
    // K4: grid (B, 32) x 256
    {
        dim3 g(NB, NV / K4_ROWS);
        k4_out<<<g, 256, 0, stream>>>(x, ewbuf, Gp, W_out, b_out, out);
    }
}

// Round 7
// 41.191 us; speedup vs baseline: 1.2031x; 1.0308x over previous
//
#include <hip/hip_runtime.h>
#include <hip/hip_bf16.h>
#include <math.h>

#define NB 32      // B
#define NV 1024    // V
#define NFT 16     // F
#define NA 32      // A
#define NP 64      // P
#define NOUT 128   // NF
#define NC 96      // C = P + A
#define NC2 192    // 2C

#define NSPLIT 16            // V splits
#define VPB 64               // NV/NSPLIT rows per block

typedef __attribute__((ext_vector_type(8))) short bf16x8;
typedef __attribute__((ext_vector_type(4))) float f32x4;

// ---------------------------------------------------------------------------
// K2p: fused vertex transform + partial (max,sum) aggregation  (unchanged R6)
// ---------------------------------------------------------------------------
__global__ void k2p(const float* __restrict__ x,
                    const float* __restrict__ W_flr,
                    const float* __restrict__ b_flr,
                    const float* __restrict__ W_s,
                    const float* __restrict__ b_s,
                    float* __restrict__ ewbuf,
                    float* __restrict__ part) {
    __shared__ float xs[VPB][NFT];   // 4 KB
    __shared__ float fs[VPB][NC];    // 24 KB

    int b = blockIdx.x, vs = blockIdx.y, tid = threadIdx.x;
    int rowbase = b * NV + vs * VPB;

    {
        const float4* xsrc = (const float4*)(x + (size_t)rowbase * NFT);
        ((float4*)xs)[tid] = xsrc[tid];
    }
    __syncthreads();

    {
        int c  = tid & 127;
        int rh = tid >> 7;
        if (c < NC) {
            float Wcol[NFT], bias;
            if (c < NP) {
                bias = b_flr[c];
#pragma unroll
                for (int k = 0; k < NFT; ++k) Wcol[k] = W_flr[k * NP + c];
            } else {
                int a = c - NP;
                bias = b_s[a];
#pragma unroll
                for (int k = 0; k < NFT; ++k) Wcol[k] = W_s[k * NA + a];
            }
#pragma unroll
            for (int r0 = 0; r0 < 32; ++r0) {
                int r = rh * 32 + r0;
                float xr[NFT];
#pragma unroll
                for (int q = 0; q < 4; ++q)
                    ((float4*)xr)[q] = ((const float4*)xs[r])[q];
                float acc = bias;
#pragma unroll
                for (int k = 0; k < NFT; ++k)
                    acc = fmaf(xr[k], Wcol[k], acc);
                if (c >= NP) {
                    acc = __expf(-acc * acc);
                    ewbuf[(size_t)(rowbase + r) * NA + (c - NP)] = acc;
                }
                fs[r][c] = acc;
            }
        }
    }
    __syncthreads();

    int at = tid >> 5, ct = tid & 31;
    int cbase = ct * 3;
    float sm[4][3], mx[4][3];
#pragma unroll
    for (int i = 0; i < 4; ++i)
#pragma unroll
        for (int j = 0; j < 3; ++j) { sm[i][j] = 0.f; mx[i][j] = -INFINITY; }

    for (int r = 0; r < VPB; ++r) {
        float4 e4 = *(const float4*)&fs[r][NP + at * 4];
        float f0 = fs[r][cbase], f1 = fs[r][cbase + 1], f2 = fs[r][cbase + 2];
        float ee[4] = {e4.x, e4.y, e4.z, e4.w};
#pragma unroll
        for (int i = 0; i < 4; ++i) {
            float p0 = ee[i] * f0, p1 = ee[i] * f1, p2 = ee[i] * f2;
            sm[i][0] += p0; sm[i][1] += p1; sm[i][2] += p2;
            mx[i][0] = fmaxf(mx[i][0], p0);
            mx[i][1] = fmaxf(mx[i][1], p1);
            mx[i][2] = fmaxf(mx[i][2], p2);
        }
    }

    float* pb = part + (size_t)((b * NSPLIT + vs) * NA) * NC2;
#pragma unroll
    for (int i = 0; i < 4; ++i) {
        int a = at * 4 + i;
#pragma unroll
        for (int j = 0; j < 3; ++j) {
            pb[a * NC2 + cbase + j]      = mx[i][j];
            pb[a * NC2 + NC + cbase + j] = sm[i][j];
        }
    }
}

// ---------------------------------------------------------------------------
// K23: combine NSPLIT partials -> agg row (in LDS) -> G matmul  (unchanged R6)
// ---------------------------------------------------------------------------
__global__ void k23(const float* __restrict__ part,
                    const float* __restrict__ W_out,
                    float* __restrict__ Gp) {
    __shared__ float aggL[NC2];
    int b = blockIdx.x, a = blockIdx.y, tid = threadIdx.x;

    {
        const float* pb = part + (size_t)(b * NSPLIT * NA + a) * NC2 + tid;
        const size_t stride = (size_t)NA * NC2;
        if (tid < NC) {
            float m = -INFINITY;
#pragma unroll
            for (int vsi = 0; vsi < NSPLIT; ++vsi)
                m = fmaxf(m, pb[vsi * stride]);
            aggL[tid] = m;
        } else {
            float s = 0.f;
#pragma unroll
            for (int vsi = 0; vsi < NSPLIT; ++vsi)
                s += pb[vsi * stride];
            aggL[tid] = s * (1.0f / (float)NV);
        }
    }
    __syncthreads();

    if (tid < NOUT) {
        int n = tid;
        const float* wr = W_out + (size_t)(NFT + a * NC2) * NOUT + n;
        float acc = W_out[(size_t)(NFT + NA * NC2 + a) * NOUT + n];
#pragma unroll 8
        for (int c = 0; c < NC2; ++c)
            acc = fmaf(aggL[c], wr[(size_t)c * NOUT], acc);
        Gp[(size_t)(b * NA + a) * NOUT + n] = acc;
    }
}

// ---------------------------------------------------------------------------
// K4 (MFMA): out[b,v,:] = tanh( [x‖ew] @ [W_head;G] + b_out )
// Per-batch GEMM M=1024, N=128, K=48 (padded to 64), bf16 hi/lo split
// (3 MFMA passes -> fp32-like accuracy). Block = 64 rows x 128 cols,
// 256 threads (4 waves, 16 rows each). A and B^T staged in LDS, XOR-swizzled.
// ---------------------------------------------------------------------------
#define MB 64
// ushort-index swizzle for [row][64] bf16 arrays: spread k-groups across banks
#define SWZ(r, k) (((r) << 6) + ((k) ^ (((r) & 7) << 3)))

__device__ inline void f2hl(float v, ushort& h, ushort& l) {
    __hip_bfloat16 hb = __float2bfloat16(v);
    float hf = __bfloat162float(hb);
    __hip_bfloat16 lb = __float2bfloat16(v - hf);
    h = *(ushort*)&hb;
    l = *(ushort*)&lb;
}

__global__ void k4_mfma(const float* __restrict__ x,
                        const float* __restrict__ ewbuf,
                        const float* __restrict__ Gp,
                        const float* __restrict__ W_out,
                        const float* __restrict__ b_out,
                        float* __restrict__ out) {
    __shared__ ushort AsH[MB * 64], AsL[MB * 64];     // 8 KB each
    __shared__ ushort BsH[NOUT * 64], BsL[NOUT * 64]; // 16 KB each
    __shared__ float  bs[NOUT];

    int rb = blockIdx.x;          // row-block within batch (0..15)
    int b  = blockIdx.y;
    int tid = threadIdx.x;
    int rowbase = b * NV + rb * MB;

    // ---- stage A: x part (k=0..15), 256 float4 ----
    {
        float4 v = ((const float4*)(x + (size_t)rowbase * NFT))[tid];
        int r = tid >> 2, kq = (tid & 3) * 4;
        float vv[4] = {v.x, v.y, v.z, v.w};
        ushort h[4], l[4];
#pragma unroll
        for (int j = 0; j < 4; ++j) f2hl(vv[j], h[j], l[j]);
        *(uint*)&AsH[SWZ(r, kq)]     = (uint)h[0] | ((uint)h[1] << 16);
        *(uint*)&AsH[SWZ(r, kq + 2)] = (uint)h[2] | ((uint)h[3] << 16);
        *(uint*)&AsL[SWZ(r, kq)]     = (uint)l[0] | ((uint)l[1] << 16);
        *(uint*)&AsL[SWZ(r, kq + 2)] = (uint)l[2] | ((uint)l[3] << 16);
    }
    // ---- stage A: ew part (k=16..47), 512 float4 ----
    {
        const float4* es4 = (const float4*)(ewbuf + (size_t)rowbase * NA);
#pragma unroll
        for (int t = 0; t < 2; ++t) {
            int i = tid * 2 + t;
            float4 v = es4[i];
            int r = i >> 3, kq = 16 + (i & 7) * 4;
            float vv[4] = {v.x, v.y, v.z, v.w};
            ushort h[4], l[4];
#pragma unroll
            for (int j = 0; j < 4; ++j) f2hl(vv[j], h[j], l[j]);
            *(uint*)&AsH[SWZ(r, kq)]     = (uint)h[0] | ((uint)h[1] << 16);
            *(uint*)&AsH[SWZ(r, kq + 2)] = (uint)h[2] | ((uint)h[3] << 16);
            *(uint*)&AsL[SWZ(r, kq)]     = (uint)l[0] | ((uint)l[1] << 16);
            *(uint*)&AsL[SWZ(r, kq + 2)] = (uint)l[2] | ((uint)l[3] << 16);
        }
    }
    // ---- stage A: zero tail (k=48..63) ----
    {
#pragma unroll
        for (int t = 0; t < 2; ++t) {
            int i = tid * 2 + t;              // 0..511
            int r = i >> 3, kq = 48 + (i & 7) * 2;
            *(uint*)&AsH[SWZ(r, kq)] = 0u;
            *(uint*)&AsL[SWZ(r, kq)] = 0u;
        }
    }
    // ---- stage B^T: W_head (k=0..15), 512 float4 of W_out rows 0..15 ----
    {
#pragma unroll
        for (int t = 0; t < 2; ++t) {
            int i = tid * 2 + t;              // 0..511
            int k = i >> 5, nq = (i & 31) * 4;
            float4 v = ((const float4*)W_out)[i];
            float vv[4] = {v.x, v.y, v.z, v.w};
#pragma unroll
            for (int j = 0; j < 4; ++j) {
                ushort h, l;
                f2hl(vv[j], h, l);
                BsH[SWZ(nq + j, k)] = h;
                BsL[SWZ(nq + j, k)] = l;
            }
        }
    }
    // ---- stage B^T: Gp (k=16..47), 1024 float4 ----
    {
        const float4* gp4 = (const float4*)(Gp + (size_t)b * NA * NOUT);
#pragma unroll
        for (int t = 0; t < 4; ++t) {
            int i = tid * 4 + t;              // 0..1023
            int a = i >> 5, nq = (i & 31) * 4;
            float4 v = gp4[i];
            int k = 16 + a;
            float vv[4] = {v.x, v.y, v.z, v.w};
#pragma unroll
            for (int j = 0; j < 4; ++j) {
                ushort h, l;
                f2hl(vv[j], h, l);
                BsH[SWZ(nq + j, k)] = h;
                BsL[SWZ(nq + j, k)] = l;
            }
        }
    }
    // ---- stage B^T: zero tail (k=48..63) ----
    {
#pragma unroll
        for (int t = 0; t < 4; ++t) {
            int i = tid * 4 + t;              // 0..1023
            int n = i >> 3, kq = 48 + (i & 7) * 2;
            *(uint*)&BsH[SWZ(n, kq)] = 0u;
            *(uint*)&BsL[SWZ(n, kq)] = 0u;
        }
    }
    if (tid < NOUT) bs[tid] = b_out[tid];

    __syncthreads();

    // ---- compute: wave w handles rows w*16..w*16+15, all 8 N-tiles ----
    int w = tid >> 6, lane = tid & 63;
    int r16 = lane & 15, kg = lane >> 4, k0 = kg * 8;
    int arow = w * 16 + r16;

    bf16x8 AH0 = *(const bf16x8*)&AsH[SWZ(arow, k0)];
    bf16x8 AH1 = *(const bf16x8*)&AsH[SWZ(arow, 32 + k0)];
    bf16x8 AL0 = *(const bf16x8*)&AsL[SWZ(arow, k0)];
    bf16x8 AL1 = *(const bf16x8*)&AsL[SWZ(arow, 32 + k0)];

    int orow0 = rowbase + w * 16 + kg * 4;

#pragma unroll
    for (int nt = 0; nt < 8; ++nt) {
        int n = nt * 16 + r16;
        bf16x8 BH0 = *(const bf16x8*)&BsH[SWZ(n, k0)];
        bf16x8 BH1 = *(const bf16x8*)&BsH[SWZ(n, 32 + k0)];
        bf16x8 BL0 = *(const bf16x8*)&BsL[SWZ(n, k0)];
        bf16x8 BL1 = *(const bf16x8*)&BsL[SWZ(n, 32 + k0)];
        float bias = bs[n];
        f32x4 acc = {bias, bias, bias, bias};
        acc = __builtin_amdgcn_mfma_f32_16x16x32_bf16(AH0, BH0, acc, 0, 0, 0);
        acc = __builtin_amdgcn_mfma_f32_16x16x32_bf16(AL0, BH0, acc, 0, 0, 0);
        acc = __builtin_amdgcn_mfma_f32_16x16x32_bf16(AH0, BL0, acc, 0, 0, 0);
        acc = __builtin_amdgcn_mfma_f32_16x16x32_bf16(AH1, BH1, acc, 0, 0, 0);
        acc = __builtin_amdgcn_mfma_f32_16x16x32_bf16(AL1, BH1, acc, 0, 0, 0);
        acc = __builtin_amdgcn_mfma_f32_16x16x32_bf16(AH1, BL1, acc, 0, 0, 0);
#pragma unroll
        for (int rg = 0; rg < 4; ++rg) {
            float s = acc[rg];
            s = fminf(fmaxf(s, -15.f), 15.f);
            float e = __expf(2.f * s);
            out[(size_t)(orow0 + rg) * NOUT + n] =
                (e - 1.f) * __builtin_amdgcn_rcpf(e + 1.f);
        }
    }
}

// ---------------------------------------------------------------------------
extern "C" void kernel_launch(void* const* d_in, const int* in_sizes, int n_in,
                              void* d_out, int out_size, void* d_ws, size_t ws_size,
                              hipStream_t stream) {
    const float* x     = (const float*)d_in[0];
    const float* W_flr = (const float*)d_in[1];
    const float* b_flr = (const float*)d_in[2];
    const float* W_s   = (const float*)d_in[3];
    const float* b_s   = (const float*)d_in[4];
    const float* W_out = (const float*)d_in[5];
    const float* b_out = (const float*)d_in[6];
    float* out = (float*)d_out;

    // workspace layout (floats)
    float* ewbuf = (float*)d_ws;                              // B*V*32        = 1,048,576
    float* part  = ewbuf + (size_t)NB * NV * NA;              // 512*32*192    = 3,145,728
    float* Gp    = part  + (size_t)NB * NSPLIT * NA * NC2;    // B*A*128       =   131,072

    // K2p: grid (B, 16) x 256
    {
        dim3 g(NB, NSPLIT);
        k2p<<<g, 256, 0, stream>>>(x, W_flr, b_flr, W_s, b_s, ewbuf, part);
    }
    // K23: grid (B, A) x 192
    {
        dim3 g(NB, NA);
        k23<<<g, 192, 0, stream>>>(part, W_out, Gp);
    }
    // K4: grid (16 row-blocks, B) x 256
    {
        dim3 g(NV / MB, NB);
        k4_mfma<<<g, 256, 0, stream>>>(x, ewbuf, Gp, W_out, b_out, out);
    }
}

// Round 8
// 38.577 us; speedup vs baseline: 1.2846x; 1.0678x over previous
//
#include <hip/hip_runtime.h>
#include <hip/hip_bf16.h>
#include <math.h>

#define NB 32      // B
#define NV 1024    // V
#define NFT 16     // F
#define NA 32      // A
#define NP 64      // P
#define NOUT 128   // NF
#define NC 96      // C = P + A
#define NC2 192    // 2C

#define NSPLIT 16            // V splits
#define VPB 64               // rows per block

typedef __attribute__((ext_vector_type(8))) short bf16x8;
typedef __attribute__((ext_vector_type(4))) float f32x4;

// ---------------------------------------------------------------------------
// K2p: fused vertex transform + partial (max,sum) aggregation.
// grid (B, 16), 256 threads.
//  phase A: unchanged (thread-per-column f-tile into LDS).
//  phase B: row-group split. Waves 0-1 -> rows 0..31, waves 2-3 -> rows 32..63.
//           Each thread owns a 4a x 6c tile (24 cells): per row 1 float4
//           e-read + 3 float2 f-reads -> 24 products (3 LDS instr).
//           Group 0 parks partials in LDS (a*100 padded stride); group 1
//           merges and writes part (same layout as before).
// ---------------------------------------------------------------------------
__global__ void k2p(const float* __restrict__ x,
                    const float* __restrict__ W_flr,
                    const float* __restrict__ b_flr,
                    const float* __restrict__ W_s,
                    const float* __restrict__ b_s,
                    float* __restrict__ ewbuf,
                    float* __restrict__ part) {
    __shared__ float xs[VPB][NFT];        // 4 KB
    __shared__ float fs[VPB][NC];         // 24 KB
    __shared__ float pcomb[(31 * 100 + 95) * 2 + 2];  // ~25.6 KB

    int b = blockIdx.x, vs = blockIdx.y, tid = threadIdx.x;
    int rowbase = b * NV + vs * VPB;

    // stage x: 64*16 = 1024 floats = 256 float4, coalesced
    {
        const float4* xsrc = (const float4*)(x + (size_t)rowbase * NFT);
        ((float4*)xs)[tid] = xsrc[tid];
    }
    __syncthreads();

    // phase A: compute f tile. c = tid&127 (<96 active), rh = tid>>7.
    {
        int c  = tid & 127;
        int rh = tid >> 7;
        if (c < NC) {
            float Wcol[NFT], bias;
            if (c < NP) {
                bias = b_flr[c];
#pragma unroll
                for (int k = 0; k < NFT; ++k) Wcol[k] = W_flr[k * NP + c];
            } else {
                int a = c - NP;
                bias = b_s[a];
#pragma unroll
                for (int k = 0; k < NFT; ++k) Wcol[k] = W_s[k * NA + a];
            }
#pragma unroll
            for (int r0 = 0; r0 < 32; ++r0) {
                int r = rh * 32 + r0;
                float xr[NFT];
#pragma unroll
                for (int q = 0; q < 4; ++q)
                    ((float4*)xr)[q] = ((const float4*)xs[r])[q];
                float acc = bias;
#pragma unroll
                for (int k = 0; k < NFT; ++k)
                    acc = fmaf(xr[k], Wcol[k], acc);
                if (c >= NP) {
                    acc = __expf(-acc * acc);
                    ewbuf[(size_t)(rowbase + r) * NA + (c - NP)] = acc;
                }
                fs[r][c] = acc;
            }
        }
    }
    __syncthreads();

    // phase B: grp = tid>>7 (0: rows 0..31, 1: rows 32..63)
    // gl = tid&127 -> at = gl>>4 (8 a-quads), ct = gl&15 (16 c-hexes)
    int grp = tid >> 7;
    int gl  = tid & 127;
    int at = gl >> 4, ct = gl & 15;
    int a0 = at * 4, c0 = ct * 6;
    int rbase = grp * 32;

    float sm[4][6], mx[4][6];
#pragma unroll
    for (int i = 0; i < 4; ++i)
#pragma unroll
        for (int j = 0; j < 6; ++j) { sm[i][j] = 0.f; mx[i][j] = -INFINITY; }

#pragma unroll 4
    for (int r0 = 0; r0 < 32; ++r0) {
        int r = rbase + r0;
        float4 e4 = *(const float4*)&fs[r][NP + a0];
        float2 fA = *(const float2*)&fs[r][c0];
        float2 fB = *(const float2*)&fs[r][c0 + 2];
        float2 fC = *(const float2*)&fs[r][c0 + 4];
        float ff[6] = {fA.x, fA.y, fB.x, fB.y, fC.x, fC.y};
        float ee[4] = {e4.x, e4.y, e4.z, e4.w};
#pragma unroll
        for (int i = 0; i < 4; ++i)
#pragma unroll
            for (int j = 0; j < 6; ++j) {
                float p = ee[i] * ff[j];
                sm[i][j] += p;
                mx[i][j] = fmaxf(mx[i][j], p);
            }
    }

    // combine the two row-groups
    if (grp == 0) {
        // park partials: pcomb[(a*100 + c)*2] = sm, +1 = mx  (b128 pairs)
#pragma unroll
        for (int i = 0; i < 4; ++i) {
            int base = ((a0 + i) * 100 + c0) * 2;
#pragma unroll
            for (int q = 0; q < 3; ++q) {
                float4 v = {sm[i][2 * q], mx[i][2 * q], sm[i][2 * q + 1], mx[i][2 * q + 1]};
                *(float4*)&pcomb[base + q * 4] = v;
            }
        }
    }
    __syncthreads();
    if (grp == 1) {
        float* pb = part + (size_t)((b * NSPLIT + vs) * NA) * NC2;
#pragma unroll
        for (int i = 0; i < 4; ++i) {
            int base = ((a0 + i) * 100 + c0) * 2;
            float osm[6], omx[6];
#pragma unroll
            for (int q = 0; q < 3; ++q) {
                float4 v = *(const float4*)&pcomb[base + q * 4];
                osm[2 * q] = v.x; omx[2 * q] = v.y;
                osm[2 * q + 1] = v.z; omx[2 * q + 1] = v.w;
            }
            int a = a0 + i;
#pragma unroll
            for (int q = 0; q < 3; ++q) {
                float2 vm = {fmaxf(mx[i][2 * q], omx[2 * q]),
                             fmaxf(mx[i][2 * q + 1], omx[2 * q + 1])};
                float2 vsum = {sm[i][2 * q] + osm[2 * q],
                               sm[i][2 * q + 1] + osm[2 * q + 1]};
                *(float2*)&pb[a * NC2 + c0 + 2 * q]      = vm;
                *(float2*)&pb[a * NC2 + NC + c0 + 2 * q] = vsum;
            }
        }
    }
}

// ---------------------------------------------------------------------------
// K23: combine NSPLIT partials -> agg row (in LDS) -> G matmul  (unchanged)
// ---------------------------------------------------------------------------
__global__ void k23(const float* __restrict__ part,
                    const float* __restrict__ W_out,
                    float* __restrict__ Gp) {
    __shared__ float aggL[NC2];
    int b = blockIdx.x, a = blockIdx.y, tid = threadIdx.x;

    {
        const float* pb = part + (size_t)(b * NSPLIT * NA + a) * NC2 + tid;
        const size_t stride = (size_t)NA * NC2;
        if (tid < NC) {
            float m = -INFINITY;
#pragma unroll
            for (int vsi = 0; vsi < NSPLIT; ++vsi)
                m = fmaxf(m, pb[vsi * stride]);
            aggL[tid] = m;
        } else {
            float s = 0.f;
#pragma unroll
            for (int vsi = 0; vsi < NSPLIT; ++vsi)
                s += pb[vsi * stride];
            aggL[tid] = s * (1.0f / (float)NV);
        }
    }
    __syncthreads();

    if (tid < NOUT) {
        int n = tid;
        const float* wr = W_out + (size_t)(NFT + a * NC2) * NOUT + n;
        float acc = W_out[(size_t)(NFT + NA * NC2 + a) * NOUT + n];
#pragma unroll 8
        for (int c = 0; c < NC2; ++c)
            acc = fmaf(aggL[c], wr[(size_t)c * NOUT], acc);
        Gp[(size_t)(b * NA + a) * NOUT + n] = acc;
    }
}

// ---------------------------------------------------------------------------
// K4 (MFMA): out[b,v,:] = tanh( [x‖ew] @ [W_head;G] + b_out )
// bf16 hi/lo split, 3 MFMA passes. A-side swizzle unchanged; B-side swizzle
// now has a second term ((n>>3)&7) so transposed ds_write_b16 staging
// spreads across banks (old (n&7) term is lane-constant in the write pattern).
// ---------------------------------------------------------------------------
#define MB 64
#define SWZ(r, k)  (((r) << 6) + ((k) ^ (((r) & 7) << 3)))
#define SWZB(n, k) (((n) << 6) + ((k) ^ (((((n) >> 3) & 7) ^ ((n) & 7)) << 3)))

__device__ inline void f2hl(float v, ushort& h, ushort& l) {
    __hip_bfloat16 hb = __float2bfloat16(v);
    float hf = __bfloat162float(hb);
    __hip_bfloat16 lb = __float2bfloat16(v - hf);
    h = *(ushort*)&hb;
    l = *(ushort*)&lb;
}

__global__ void k4_mfma(const float* __restrict__ x,
                        const float* __restrict__ ewbuf,
                        const float* __restrict__ Gp,
                        const float* __restrict__ W_out,
                        const float* __restrict__ b_out,
                        float* __restrict__ out) {
    __shared__ ushort AsH[MB * 64], AsL[MB * 64];     // 8 KB each
    __shared__ ushort BsH[NOUT * 64], BsL[NOUT * 64]; // 16 KB each
    __shared__ float  bs[NOUT];

    int rb = blockIdx.x;          // row-block within batch (0..15)
    int b  = blockIdx.y;
    int tid = threadIdx.x;
    int rowbase = b * NV + rb * MB;

    // ---- stage A: x part (k=0..15) ----
    {
        float4 v = ((const float4*)(x + (size_t)rowbase * NFT))[tid];
        int r = tid >> 2, kq = (tid & 3) * 4;
        float vv[4] = {v.x, v.y, v.z, v.w};
        ushort h[4], l[4];
#pragma unroll
        for (int j = 0; j < 4; ++j) f2hl(vv[j], h[j], l[j]);
        *(uint*)&AsH[SWZ(r, kq)]     = (uint)h[0] | ((uint)h[1] << 16);
        *(uint*)&AsH[SWZ(r, kq + 2)] = (uint)h[2] | ((uint)h[3] << 16);
        *(uint*)&AsL[SWZ(r, kq)]     = (uint)l[0] | ((uint)l[1] << 16);
        *(uint*)&AsL[SWZ(r, kq + 2)] = (uint)l[2] | ((uint)l[3] << 16);
    }
    // ---- stage A: ew part (k=16..47) ----
    {
        const float4* es4 = (const float4*)(ewbuf + (size_t)rowbase * NA);
#pragma unroll
        for (int t = 0; t < 2; ++t) {
            int i = tid * 2 + t;
            float4 v = es4[i];
            int r = i >> 3, kq = 16 + (i & 7) * 4;
            float vv[4] = {v.x, v.y, v.z, v.w};
            ushort h[4], l[4];
#pragma unroll
            for (int j = 0; j < 4; ++j) f2hl(vv[j], h[j], l[j]);
            *(uint*)&AsH[SWZ(r, kq)]     = (uint)h[0] | ((uint)h[1] << 16);
            *(uint*)&AsH[SWZ(r, kq + 2)] = (uint)h[2] | ((uint)h[3] << 16);
            *(uint*)&AsL[SWZ(r, kq)]     = (uint)l[0] | ((uint)l[1] << 16);
            *(uint*)&AsL[SWZ(r, kq + 2)] = (uint)l[2] | ((uint)l[3] << 16);
        }
    }
    // ---- stage A: zero tail (k=48..63) ----
    {
#pragma unroll
        for (int t = 0; t < 2; ++t) {
            int i = tid * 2 + t;
            int r = i >> 3, kq = 48 + (i & 7) * 2;
            *(uint*)&AsH[SWZ(r, kq)] = 0u;
            *(uint*)&AsL[SWZ(r, kq)] = 0u;
        }
    }
    // ---- stage B^T: W_head (k=0..15) ----
    {
#pragma unroll
        for (int t = 0; t < 2; ++t) {
            int i = tid * 2 + t;
            int k = i >> 5, nq = (i & 31) * 4;
            float4 v = ((const float4*)W_out)[i];
            float vv[4] = {v.x, v.y, v.z, v.w};
#pragma unroll
            for (int j = 0; j < 4; ++j) {
                ushort h, l;
                f2hl(vv[j], h, l);
                BsH[SWZB(nq + j, k)] = h;
                BsL[SWZB(nq + j, k)] = l;
            }
        }
    }
    // ---- stage B^T: Gp (k=16..47) ----
    {
        const float4* gp4 = (const float4*)(Gp + (size_t)b * NA * NOUT);
#pragma unroll
        for (int t = 0; t < 4; ++t) {
            int i = tid * 4 + t;
            int a = i >> 5, nq = (i & 31) * 4;
            float4 v = gp4[i];
            int k = 16 + a;
            float vv[4] = {v.x, v.y, v.z, v.w};
#pragma unroll
            for (int j = 0; j < 4; ++j) {
                ushort h, l;
                f2hl(vv[j], h, l);
                BsH[SWZB(nq + j, k)] = h;
                BsL[SWZB(nq + j, k)] = l;
            }
        }
    }
    // ---- stage B^T: zero tail (k=48..63) ----
    {
#pragma unroll
        for (int t = 0; t < 4; ++t) {
            int i = tid * 4 + t;
            int n = i >> 3, kq = 48 + (i & 7) * 2;
            *(uint*)&BsH[SWZB(n, kq)] = 0u;
            *(uint*)&BsL[SWZB(n, kq)] = 0u;
        }
    }
    if (tid < NOUT) bs[tid] = b_out[tid];

    __syncthreads();

    // ---- compute ----
    int w = tid >> 6, lane = tid & 63;
    int r16 = lane & 15, kg = lane >> 4, k0 = kg * 8;
    int arow = w * 16 + r16;

    bf16x8 AH0 = *(const bf16x8*)&AsH[SWZ(arow, k0)];
    bf16x8 AH1 = *(const bf16x8*)&AsH[SWZ(arow, 32 + k0)];
    bf16x8 AL0 = *(const bf16x8*)&AsL[SWZ(arow, k0)];
    bf16x8 AL1 = *(const bf16x8*)&AsL[SWZ(arow, 32 + k0)];

    int orow0 = rowbase + w * 16 + kg * 4;

#pragma unroll
    for (int nt = 0; nt < 8; ++nt) {
        int n = nt * 16 + r16;
        bf16x8 BH0 = *(const bf16x8*)&BsH[SWZB(n, k0)];
        bf16x8 BH1 = *(const bf16x8*)&BsH[SWZB(n, 32 + k0)];
        bf16x8 BL0 = *(const bf16x8*)&BsL[SWZB(n, k0)];
        bf16x8 BL1 = *(const bf16x8*)&BsL[SWZB(n, 32 + k0)];
        float bias = bs[n];
        f32x4 acc = {bias, bias, bias, bias};
        acc = __builtin_amdgcn_mfma_f32_16x16x32_bf16(AH0, BH0, acc, 0, 0, 0);
        acc = __builtin_amdgcn_mfma_f32_16x16x32_bf16(AL0, BH0, acc, 0, 0, 0);
        acc = __builtin_amdgcn_mfma_f32_16x16x32_bf16(AH0, BL0, acc, 0, 0, 0);
        acc = __builtin_amdgcn_mfma_f32_16x16x32_bf16(AH1, BH1, acc, 0, 0, 0);
        acc = __builtin_amdgcn_mfma_f32_16x16x32_bf16(AL1, BH1, acc, 0, 0, 0);
        acc = __builtin_amdgcn_mfma_f32_16x16x32_bf16(AH1, BL1, acc, 0, 0, 0);
#pragma unroll
        for (int rg = 0; rg < 4; ++rg) {
            float s = acc[rg];
            s = fminf(fmaxf(s, -15.f), 15.f);
            float e = __expf(2.f * s);
            out[(size_t)(orow0 + rg) * NOUT + n] =
                (e - 1.f) * __builtin_amdgcn_rcpf(e + 1.f);
        }
    }
}

// ---------------------------------------------------------------------------
extern "C" void kernel_launch(void* const* d_in, const int* in_sizes, int n_in,
                              void* d_out, int out_size, void* d_ws, size_t ws_size,
                              hipStream_t stream) {
    const float* x     = (const float*)d_in[0];
    const float* W_flr = (const float*)d_in[1];
    const float* b_flr = (const float*)d_in[2];
    const float* W_s   = (const float*)d_in[3];
    const float* b_s   = (const float*)d_in[4];
    const float* W_out = (const float*)d_in[5];
    const float* b_out = (const float*)d_in[6];
    float* out = (float*)d_out;

    // workspace layout (floats)
    float* ewbuf = (float*)d_ws;                              // B*V*32     = 1,048,576
    float* part  = ewbuf + (size_t)NB * NV * NA;              // 512*32*192 = 3,145,728
    float* Gp    = part  + (size_t)NB * NSPLIT * NA * NC2;    // B*A*128    =   131,072

    // K2p: grid (B, 16) x 256
    {
        dim3 g(NB, NSPLIT);
        k2p<<<g, 256, 0, stream>>>(x, W_flr, b_flr, W_s, b_s, ewbuf, part);
    }
    // K23: grid (B, A) x 192
    {
        dim3 g(NB, NA);
        k23<<<g, 192, 0, stream>>>(part, W_out, Gp);
    }
    // K4: grid (16 row-blocks, B) x 256
    {
        dim3 g(NV / MB, NB);
        k4_mfma<<<g, 256, 0, stream>>>(x, ewbuf, Gp, W_out, b_out, out);
    }
}

// Round 9
// 38.066 us; speedup vs baseline: 1.3019x; 1.0134x over previous
//
#include <hip/hip_runtime.h>
#include <hip/hip_bf16.h>
#include <math.h>

#define NB 32      // B
#define NV 1024    // V
#define NFT 16     // F
#define NA 32      // A
#define NP 64      // P
#define NOUT 128   // NF
#define NC 96      // C = P + A
#define NC2 192    // 2C

#define NSPLIT 16            // V splits
#define VPB 64               // rows per block

typedef __attribute__((ext_vector_type(8))) short bf16x8;
typedef __attribute__((ext_vector_type(4))) float f32x4;

// ---------------------------------------------------------------------------
// K2p: fused vertex transform + partial (max,sum) aggregation.
// grid (B, 16), **512 threads** (8 waves) -> 16 waves/CU (was 8).
//  phase A: c = tid&127 (<96 active), rh = tid>>7 (4 row-quarters of 16).
//  phase B: thread owns 1a x 6c tile: per row 1 b32 e-read + 3 float2
//           f-reads, 18 VALU. Direct part writes (no pcomb, no merge).
// part layout: part[((b*16+vs)*32 + a)*192 + c] = max ; +96+c = sum
// ---------------------------------------------------------------------------
__global__ __launch_bounds__(512, 2)
void k2p(const float* __restrict__ x,
         const float* __restrict__ W_flr,
         const float* __restrict__ b_flr,
         const float* __restrict__ W_s,
         const float* __restrict__ b_s,
         float* __restrict__ ewbuf,
         float* __restrict__ part) {
    __shared__ float xs[VPB][NFT];        // 4 KB
    __shared__ float fs[VPB][NC];         // 24 KB

    int b = blockIdx.x, vs = blockIdx.y, tid = threadIdx.x;
    int rowbase = b * NV + vs * VPB;

    // stage x: 64*16 = 1024 floats = 256 float4, coalesced
    if (tid < 256) {
        const float4* xsrc = (const float4*)(x + (size_t)rowbase * NFT);
        ((float4*)xs)[tid] = xsrc[tid];
    }
    __syncthreads();

    // phase A: c = tid&127 (<96 active), rh = tid>>7 -> rows rh*16..rh*16+15
    {
        int c  = tid & 127;
        int rh = tid >> 7;
        if (c < NC) {
            float Wcol[NFT], bias;
            if (c < NP) {
                bias = b_flr[c];
#pragma unroll
                for (int k = 0; k < NFT; ++k) Wcol[k] = W_flr[k * NP + c];
            } else {
                int a = c - NP;
                bias = b_s[a];
#pragma unroll
                for (int k = 0; k < NFT; ++k) Wcol[k] = W_s[k * NA + a];
            }
#pragma unroll
            for (int r0 = 0; r0 < 16; ++r0) {
                int r = rh * 16 + r0;
                float xr[NFT];
#pragma unroll
                for (int q = 0; q < 4; ++q)
                    ((float4*)xr)[q] = ((const float4*)xs[r])[q];
                float acc = bias;
#pragma unroll
                for (int k = 0; k < NFT; ++k)
                    acc = fmaf(xr[k], Wcol[k], acc);
                if (c >= NP) {
                    acc = __expf(-acc * acc);
                    ewbuf[(size_t)(rowbase + r) * NA + (c - NP)] = acc;
                }
                fs[r][c] = acc;
            }
        }
    }
    __syncthreads();

    // phase B: thread owns 1a x 6c. a = tid>>4 (32), c0 = (tid&15)*6.
    int a  = tid >> 4;
    int c0 = (tid & 15) * 6;
    int ea = NP + a;

    float sm[6], mx[6];
#pragma unroll
    for (int j = 0; j < 6; ++j) { sm[j] = 0.f; mx[j] = -INFINITY; }

#pragma unroll 4
    for (int r = 0; r < VPB; ++r) {
        float e = fs[r][ea];
        float2 fA = *(const float2*)&fs[r][c0];
        float2 fB = *(const float2*)&fs[r][c0 + 2];
        float2 fC = *(const float2*)&fs[r][c0 + 4];
        float ff[6] = {fA.x, fA.y, fB.x, fB.y, fC.x, fC.y};
#pragma unroll
        for (int j = 0; j < 6; ++j) {
            float p = e * ff[j];
            sm[j] += p;
            mx[j] = fmaxf(mx[j], p);
        }
    }

    float* pb = part + (size_t)((b * NSPLIT + vs) * NA + a) * NC2;
#pragma unroll
    for (int q = 0; q < 3; ++q) {
        float2 vm = {mx[2 * q], mx[2 * q + 1]};
        float2 vsum = {sm[2 * q], sm[2 * q + 1]};
        *(float2*)&pb[c0 + 2 * q]      = vm;
        *(float2*)&pb[NC + c0 + 2 * q] = vsum;
    }
}

// ---------------------------------------------------------------------------
// K23: combine NSPLIT partials -> agg row (in LDS) -> G matmul  (unchanged)
// ---------------------------------------------------------------------------
__global__ void k23(const float* __restrict__ part,
                    const float* __restrict__ W_out,
                    float* __restrict__ Gp) {
    __shared__ float aggL[NC2];
    int b = blockIdx.x, a = blockIdx.y, tid = threadIdx.x;

    {
        const float* pb = part + (size_t)(b * NSPLIT * NA + a) * NC2 + tid;
        const size_t stride = (size_t)NA * NC2;
        if (tid < NC) {
            float m = -INFINITY;
#pragma unroll
            for (int vsi = 0; vsi < NSPLIT; ++vsi)
                m = fmaxf(m, pb[vsi * stride]);
            aggL[tid] = m;
        } else {
            float s = 0.f;
#pragma unroll
            for (int vsi = 0; vsi < NSPLIT; ++vsi)
                s += pb[vsi * stride];
            aggL[tid] = s * (1.0f / (float)NV);
        }
    }
    __syncthreads();

    if (tid < NOUT) {
        int n = tid;
        const float* wr = W_out + (size_t)(NFT + a * NC2) * NOUT + n;
        float acc = W_out[(size_t)(NFT + NA * NC2 + a) * NOUT + n];
#pragma unroll 8
        for (int c = 0; c < NC2; ++c)
            acc = fmaf(aggL[c], wr[(size_t)c * NOUT], acc);
        Gp[(size_t)(b * NA + a) * NOUT + n] = acc;
    }
}

// ---------------------------------------------------------------------------
// K4 (MFMA): out[b,v,:] = tanh( [x‖ew] @ [W_head;G] + b_out )   (unchanged R8)
// ---------------------------------------------------------------------------
#define MB 64
#define SWZ(r, k)  (((r) << 6) + ((k) ^ (((r) & 7) << 3)))
#define SWZB(n, k) (((n) << 6) + ((k) ^ (((((n) >> 3) & 7) ^ ((n) & 7)) << 3)))

__device__ inline void f2hl(float v, ushort& h, ushort& l) {
    __hip_bfloat16 hb = __float2bfloat16(v);
    float hf = __bfloat162float(hb);
    __hip_bfloat16 lb = __float2bfloat16(v - hf);
    h = *(ushort*)&hb;
    l = *(ushort*)&lb;
}

__global__ void k4_mfma(const float* __restrict__ x,
                        const float* __restrict__ ewbuf,
                        const float* __restrict__ Gp,
                        const float* __restrict__ W_out,
                        const float* __restrict__ b_out,
                        float* __restrict__ out) {
    __shared__ ushort AsH[MB * 64], AsL[MB * 64];     // 8 KB each
    __shared__ ushort BsH[NOUT * 64], BsL[NOUT * 64]; // 16 KB each
    __shared__ float  bs[NOUT];

    int rb = blockIdx.x;          // row-block within batch (0..15)
    int b  = blockIdx.y;
    int tid = threadIdx.x;
    int rowbase = b * NV + rb * MB;

    // ---- stage A: x part (k=0..15) ----
    {
        float4 v = ((const float4*)(x + (size_t)rowbase * NFT))[tid];
        int r = tid >> 2, kq = (tid & 3) * 4;
        float vv[4] = {v.x, v.y, v.z, v.w};
        ushort h[4], l[4];
#pragma unroll
        for (int j = 0; j < 4; ++j) f2hl(vv[j], h[j], l[j]);
        *(uint*)&AsH[SWZ(r, kq)]     = (uint)h[0] | ((uint)h[1] << 16);
        *(uint*)&AsH[SWZ(r, kq + 2)] = (uint)h[2] | ((uint)h[3] << 16);
        *(uint*)&AsL[SWZ(r, kq)]     = (uint)l[0] | ((uint)l[1] << 16);
        *(uint*)&AsL[SWZ(r, kq + 2)] = (uint)l[2] | ((uint)l[3] << 16);
    }
    // ---- stage A: ew part (k=16..47) ----
    {
        const float4* es4 = (const float4*)(ewbuf + (size_t)rowbase * NA);
#pragma unroll
        for (int t = 0; t < 2; ++t) {
            int i = tid * 2 + t;
            float4 v = es4[i];
            int r = i >> 3, kq = 16 + (i & 7) * 4;
            float vv[4] = {v.x, v.y, v.z, v.w};
            ushort h[4], l[4];
#pragma unroll
            for (int j = 0; j < 4; ++j) f2hl(vv[j], h[j], l[j]);
            *(uint*)&AsH[SWZ(r, kq)]     = (uint)h[0] | ((uint)h[1] << 16);
            *(uint*)&AsH[SWZ(r, kq + 2)] = (uint)h[2] | ((uint)h[3] << 16);
            *(uint*)&AsL[SWZ(r, kq)]     = (uint)l[0] | ((uint)l[1] << 16);
            *(uint*)&AsL[SWZ(r, kq + 2)] = (uint)l[2] | ((uint)l[3] << 16);
        }
    }
    // ---- stage A: zero tail (k=48..63) ----
    {
#pragma unroll
        for (int t = 0; t < 2; ++t) {
            int i = tid * 2 + t;
            int r = i >> 3, kq = 48 + (i & 7) * 2;
            *(uint*)&AsH[SWZ(r, kq)] = 0u;
            *(uint*)&AsL[SWZ(r, kq)] = 0u;
        }
    }
    // ---- stage B^T: W_head (k=0..15) ----
    {
#pragma unroll
        for (int t = 0; t < 2; ++t) {
            int i = tid * 2 + t;
            int k = i >> 5, nq = (i & 31) * 4;
            float4 v = ((const float4*)W_out)[i];
            float vv[4] = {v.x, v.y, v.z, v.w};
#pragma unroll
            for (int j = 0; j < 4; ++j) {
                ushort h, l;
                f2hl(vv[j], h, l);
                BsH[SWZB(nq + j, k)] = h;
                BsL[SWZB(nq + j, k)] = l;
            }
        }
    }
    // ---- stage B^T: Gp (k=16..47) ----
    {
        const float4* gp4 = (const float4*)(Gp + (size_t)b * NA * NOUT);
#pragma unroll
        for (int t = 0; t < 4; ++t) {
            int i = tid * 4 + t;
            int a = i >> 5, nq = (i & 31) * 4;
            float4 v = gp4[i];
            int k = 16 + a;
            float vv[4] = {v.x, v.y, v.z, v.w};
#pragma unroll
            for (int j = 0; j < 4; ++j) {
                ushort h, l;
                f2hl(vv[j], h, l);
                BsH[SWZB(nq + j, k)] = h;
                BsL[SWZB(nq + j, k)] = l;
            }
        }
    }
    // ---- stage B^T: zero tail (k=48..63) ----
    {
#pragma unroll
        for (int t = 0; t < 4; ++t) {
            int i = tid * 4 + t;
            int n = i >> 3, kq = 48 + (i & 7) * 2;
            *(uint*)&BsH[SWZB(n, kq)] = 0u;
            *(uint*)&BsL[SWZB(n, kq)] = 0u;
        }
    }
    if (tid < NOUT) bs[tid] = b_out[tid];

    __syncthreads();

    // ---- compute ----
    int w = tid >> 6, lane = tid & 63;
    int r16 = lane & 15, kg = lane >> 4, k0 = kg * 8;
    int arow = w * 16 + r16;

    bf16x8 AH0 = *(const bf16x8*)&AsH[SWZ(arow, k0)];
    bf16x8 AH1 = *(const bf16x8*)&AsH[SWZ(arow, 32 + k0)];
    bf16x8 AL0 = *(const bf16x8*)&AsL[SWZ(arow, k0)];
    bf16x8 AL1 = *(const bf16x8*)&AsL[SWZ(arow, 32 + k0)];

    int orow0 = rowbase + w * 16 + kg * 4;

#pragma unroll
    for (int nt = 0; nt < 8; ++nt) {
        int n = nt * 16 + r16;
        bf16x8 BH0 = *(const bf16x8*)&BsH[SWZB(n, k0)];
        bf16x8 BH1 = *(const bf16x8*)&BsH[SWZB(n, 32 + k0)];
        bf16x8 BL0 = *(const bf16x8*)&BsL[SWZB(n, k0)];
        bf16x8 BL1 = *(const bf16x8*)&BsL[SWZB(n, 32 + k0)];
        float bias = bs[n];
        f32x4 acc = {bias, bias, bias, bias};
        acc = __builtin_amdgcn_mfma_f32_16x16x32_bf16(AH0, BH0, acc, 0, 0, 0);
        acc = __builtin_amdgcn_mfma_f32_16x16x32_bf16(AL0, BH0, acc, 0, 0, 0);
        acc = __builtin_amdgcn_mfma_f32_16x16x32_bf16(AH0, BL0, acc, 0, 0, 0);
        acc = __builtin_amdgcn_mfma_f32_16x16x32_bf16(AH1, BH1, acc, 0, 0, 0);
        acc = __builtin_amdgcn_mfma_f32_16x16x32_bf16(AL1, BH1, acc, 0, 0, 0);
        acc = __builtin_amdgcn_mfma_f32_16x16x32_bf16(AH1, BL1, acc, 0, 0, 0);
#pragma unroll
        for (int rg = 0; rg < 4; ++rg) {
            float s = acc[rg];
            s = fminf(fmaxf(s, -15.f), 15.f);
            float e = __expf(2.f * s);
            out[(size_t)(orow0 + rg) * NOUT + n] =
                (e - 1.f) * __builtin_amdgcn_rcpf(e + 1.f);
        }
    }
}

// ---------------------------------------------------------------------------
extern "C" void kernel_launch(void* const* d_in, const int* in_sizes, int n_in,
                              void* d_out, int out_size, void* d_ws, size_t ws_size,
                              hipStream_t stream) {
    const float* x     = (const float*)d_in[0];
    const float* W_flr = (const float*)d_in[1];
    const float* b_flr = (const float*)d_in[2];
    const float* W_s   = (const float*)d_in[3];
    const float* b_s   = (const float*)d_in[4];
    const float* W_out = (const float*)d_in[5];
    const float* b_out = (const float*)d_in[6];
    float* out = (float*)d_out;

    // workspace layout (floats)
    float* ewbuf = (float*)d_ws;                              // B*V*32     = 1,048,576
    float* part  = ewbuf + (size_t)NB * NV * NA;              // 512*32*192 = 3,145,728
    float* Gp    = part  + (size_t)NB * NSPLIT * NA * NC2;    // B*A*128    =   131,072

    // K2p: grid (B, 16) x 512
    {
        dim3 g(NB, NSPLIT);
        k2p<<<g, 512, 0, stream>>>(x, W_flr, b_flr, W_s, b_s, ewbuf, part);
    }
    // K23: grid (B, A) x 192
    {
        dim3 g(NB, NA);
        k23<<<g, 192, 0, stream>>>(part, W_out, Gp);
    }
    // K4: grid (16 row-blocks, B) x 256
    {
        dim3 g(NV / MB, NB);
        k4_mfma<<<g, 256, 0, stream>>>(x, ewbuf, Gp, W_out, b_out, out);
    }
}